// Round 1
// baseline (134.743 us; speedup 1.0000x reference)
//
#include <hip/hip_runtime.h>
#include <hip/hip_bf16.h>

// RefinementLayer2: B=2,S=384,C=4,H=128,D=768 — 3 dispatches (R4 structure).
// vs R3 (131.6us):
//  * 512-thread blocks, 2-way in-block split-K in every MFMA tile (halves the
//    exposed barrier/latency chain; doubles waves/SIMD at ~1 block/CU).
//  * tanh_h stored bf16 [m][k]; h_a stored bf16 PRE-TRANSPOSED h_aT[b,c,h,a],
//    so consumer GEMMs stage with vector ushort8 copies (no f2bf, no 16-way
//    conflicted scalar transpose writes).
//  * tref atomicAdd tail -> 8 per-(c,x) partial buffers (plain stores);
//    phase2 sums partials in Es setup. Removes 786K cross-XCD atomics and the
//    tref zero-fill dependency (g1 grid z: 3 -> 2).
//  * staging LDS stride 40 -> 42 ushorts (f32-B transpose writes 16->4-way).
// ws layout (float offsets):
//   0        tanh16    (768x512 x2, bf16)   = tanh(seq@{Wp,Ua}+b)
//   393216   haT       (2,4,128,384 bf16)   = (seq@Ua+b) transposed
//   589824   tprd_s    (3072,128 f32)       = C2*tanh(h_p)@W1
//   983040   targ_s    (3072,128 bf16)      = C2*tanh(h_a)@W2
//   1179648  tref_part (8,768,128 f32)      = C2*tanh(ref)@W3 partials

#define C2 2.885390081777927f  // 2/ln(2): exp2(C2*x) = e^(2x)
#define LSH 42                 // staging LDS row stride (ushorts)
#define LSZ (64 * LSH)         // 2688 ushorts per 64x32 tile

typedef __attribute__((ext_vector_type(8))) __bf16 bf16x8;
typedef __attribute__((ext_vector_type(8))) unsigned short ushort8;
typedef __attribute__((ext_vector_type(4))) float float4v;

__device__ __forceinline__ unsigned short f2bf(float f) {
  unsigned int u = __float_as_uint(f);
  u += 0x7fffu + ((u >> 16) & 1u);
  return (unsigned short)(u >> 16);
}

__device__ __forceinline__ float fast_tanh(float x) {
  float e = __builtin_amdgcn_exp2f(C2 * x);
  return 1.0f - 2.0f * __builtin_amdgcn_rcpf(1.0f + e);
}

// 64x64-tile bf16-MFMA core, 512 threads = 2 k-groups x 4 waves (32x32 each).
// Group g covers k in [g*K/2, (g+1)*K/2); partial accs reduced by caller.
// AF: 0 = A fp32 [m][k] (f2bf staged), 1 = A bf16 [m][k] (vector copy).
// BF: 0 = B fp32 [k][n] (f2bf + transpose scalar stores),
//     1 = B bf16 [n][k] pre-transposed (vector copy).
template <int AF, int BF>
__device__ __forceinline__ void gemm_core(
    const void* __restrict__ Abase, int lda,
    const void* __restrict__ Bbase, int ldb, int K,
    unsigned short* Alds, unsigned short* Blds,
    int t, int g, int wm0, int wn0, int col16, int quad, float4v acc[2][2])
{
  const int Kh = K >> 1;
  const int ar = t >> 2, ac = (t & 3) * 8;  // 64 rows x 32 k, 8/thread
  const int bk = t >> 3, bn = (t & 7) * 8;  // f32-B: 32 k x 64 n

  const float* Afp = (const float*)Abase + (size_t)ar * lda + g * Kh + ac;
  const unsigned short* Abp =
      (const unsigned short*)Abase + (size_t)ar * lda + g * Kh + ac;
  const float* Bfp = (const float*)Bbase + (size_t)(g * Kh + bk) * ldb + bn;
  const unsigned short* Bbp =
      (const unsigned short*)Bbase + (size_t)ar * ldb + g * Kh + ac;

  float4 a0, a1, b0, b1;
  ushort8 a16, b16;
  if constexpr (AF == 0) { a0 = ((const float4*)Afp)[0]; a1 = ((const float4*)Afp)[1]; }
  else                   { a16 = *(const ushort8*)Abp; }
  if constexpr (BF == 0) { b0 = ((const float4*)Bfp)[0]; b1 = ((const float4*)Bfp)[1]; }
  else                   { b16 = *(const ushort8*)Bbp; }

  for (int k0 = 0; k0 < Kh; k0 += 32) {
    __syncthreads();
    if constexpr (AF == 0) {
      ushort8 o;
      o[0] = f2bf(a0.x); o[1] = f2bf(a0.y); o[2] = f2bf(a0.z); o[3] = f2bf(a0.w);
      o[4] = f2bf(a1.x); o[5] = f2bf(a1.y); o[6] = f2bf(a1.z); o[7] = f2bf(a1.w);
      *(ushort8*)&Alds[ar * LSH + ac] = o;
    } else {
      *(ushort8*)&Alds[ar * LSH + ac] = a16;
    }
    if constexpr (BF == 0) {
      float vv[8] = {b0.x, b0.y, b0.z, b0.w, b1.x, b1.y, b1.z, b1.w};
#pragma unroll
      for (int j = 0; j < 8; ++j) Blds[(bn + j) * LSH + bk] = f2bf(vv[j]);
    } else {
      *(ushort8*)&Blds[ar * LSH + ac] = b16;
    }
    __syncthreads();
    if (k0 + 32 < Kh) {
      if constexpr (AF == 0) {
        const float4* An = (const float4*)(Afp + k0 + 32);
        a0 = An[0]; a1 = An[1];
      } else {
        a16 = *(const ushort8*)(Abp + k0 + 32);
      }
      if constexpr (BF == 0) {
        const float4* Bn = (const float4*)(Bfp + (size_t)(k0 + 32) * ldb);
        b0 = Bn[0]; b1 = Bn[1];
      } else {
        b16 = *(const ushort8*)(Bbp + k0 + 32);
      }
    }
    bf16x8 afrag[2], bfrag[2];
#pragma unroll
    for (int i = 0; i < 2; ++i)
      afrag[i] = __builtin_bit_cast(bf16x8,
          *(const ushort8*)&Alds[(wm0 + i * 16 + col16) * LSH + quad * 8]);
#pragma unroll
    for (int j = 0; j < 2; ++j)
      bfrag[j] = __builtin_bit_cast(bf16x8,
          *(const ushort8*)&Blds[(wn0 + j * 16 + col16) * LSH + quad * 8]);
#pragma unroll
    for (int i = 0; i < 2; ++i)
#pragma unroll
      for (int j = 0; j < 2; ++j)
        acc[i][j] = __builtin_amdgcn_mfma_f32_16x16x32_bf16(
            afrag[i], bfrag[j], acc[i][j], 0, 0, 0);
  }
}

// Cross-group reduce: group1 stores its partial acc (stride-20 f32 slots,
// 16B-aligned), group0 adds. scratch aliases the staging LDS (done with it).
__device__ __forceinline__ void reduce_groups(float4v acc[2][2], float* scratch,
                                              int tid) {
  __syncthreads();
  if (tid >= 256) {
    float* s = scratch + (tid - 256) * 20;
#pragma unroll
    for (int i = 0; i < 2; ++i)
#pragma unroll
      for (int j = 0; j < 2; ++j)
        *(float4v*)&s[(i * 2 + j) * 4] = acc[i][j];
  }
  __syncthreads();
  if (tid < 256) {
    const float* s = scratch + tid * 20;
#pragma unroll
    for (int i = 0; i < 2; ++i)
#pragma unroll
      for (int j = 0; j < 2; ++j)
        acc[i][j] += *(const float4v*)&s[(i * 2 + j) * 4];
  }
}

// D1: z=0: tanh(seq@Wp+b) -> tanh16; z=1: x=seq@Ua+b -> tanh16 + haT (bf16,T).
__global__ __launch_bounds__(512) void g1_dual(
    const float* __restrict__ seq, const float* __restrict__ Wp,
    const float* __restrict__ Ua, const float* __restrict__ Wpb,
    const float* __restrict__ Uab, unsigned short* __restrict__ tanh16,
    unsigned short* __restrict__ haT)
{
  __shared__ unsigned short AB[4 * LSZ];
  const int tid = threadIdx.x;
  const int z = blockIdx.z;
  const int bn0 = blockIdx.x * 64, bm0 = blockIdx.y * 64;
  const int g = tid >> 8, t = tid & 255;
  const int wid2 = (tid >> 6) & 3, lane = tid & 63;
  const int wm0 = (wid2 >> 1) * 32, wn0 = (wid2 & 1) * 32;
  const int col16 = lane & 15, quad = lane >> 4;
  const float* B = z ? Ua : Wp;
  const float* bias = z ? Uab : Wpb;
  unsigned short* Alds = AB + (g * 2) * LSZ;
  unsigned short* Blds = AB + (g * 2 + 1) * LSZ;

  float4v acc[2][2];
#pragma unroll
  for (int i = 0; i < 2; ++i)
#pragma unroll
    for (int j = 0; j < 2; ++j) acc[i][j] = (float4v)(0.f);

  gemm_core<0, 0>(seq + (size_t)bm0 * 768, 768, B + bn0, 512, 768,
                  Alds, Blds, t, g, wm0, wn0, col16, quad, acc);
  reduce_groups(acc, (float*)AB, tid);

  if (tid < 256) {
    unsigned short* tout = tanh16 + (size_t)z * 393216;
#pragma unroll
    for (int j = 0; j < 2; ++j) {
      const int gcol = bn0 + wn0 + j * 16 + col16;
      const float bv = bias[gcol];
#pragma unroll
      for (int i = 0; i < 2; ++i) {
        const int grow0 = bm0 + wm0 + i * 16 + quad * 4;
        float x[4];
#pragma unroll
        for (int r = 0; r < 4; ++r) x[r] = acc[i][j][r] + bv;
#pragma unroll
        for (int r = 0; r < 4; ++r)
          tout[(size_t)(grow0 + r) * 512 + gcol] = f2bf(fast_tanh(x[r]));
        if (z == 1) {  // h_aT[b][c][h][a], 4 consecutive a packed per store
          const int bb = grow0 >= 384 ? 1 : 0;
          const int a0 = grow0 - bb * 384;
          const int cc = gcol >> 7, hh = gcol & 127;
          uint2 pk;
          pk.x = (unsigned)f2bf(x[0]) | ((unsigned)f2bf(x[1]) << 16);
          pk.y = (unsigned)f2bf(x[2]) | ((unsigned)f2bf(x[3]) << 16);
          *(uint2*)&haT[(size_t)((bb * 4 + cc) * 128 + hh) * 384 + a0] = pk;
        }
      }
    }
  }
}

// D2: job table, 288 blocks x 512 threads.
//  bid<96 : ref tile = base[b,:,c,:]@h_a[b,:,c,:] (64x64,K=384) -> tanh ->
//           tail MFMA: tref_part[c*2+x][rows][0:128] = C2*tanh(tile)@W3slice.
//  bid>=96: tanh_h{p,a}@W{1,2} -> tprd fp32 / targ bf16, *C2.
__global__ __launch_bounds__(512) void fused_mid(
    const float* __restrict__ base, const unsigned short* __restrict__ haT,
    const unsigned short* __restrict__ tanh16, const float* __restrict__ Wmid,
    float* __restrict__ tprd_s, unsigned short* __restrict__ targ_s,
    float* __restrict__ tref_part)
{
  __shared__ unsigned short AB[4 * LSZ];
  __shared__ unsigned short TA[64 * 72];
  __shared__ unsigned short TB[128 * 72];

  const int tid = threadIdx.x;
  const int bid = blockIdx.x;
  const int g = tid >> 8, t = tid & 255;
  const int wid2 = (tid >> 6) & 3, lane = tid & 63;
  const int wm0 = (wid2 >> 1) * 32, wn0 = (wid2 & 1) * 32;
  const int col16 = lane & 15, quad = lane >> 4;
  unsigned short* Alds = AB + (g * 2) * LSZ;
  unsigned short* Blds = AB + (g * 2 + 1) * LSZ;

  float4v acc[2][2];
#pragma unroll
  for (int i = 0; i < 2; ++i)
#pragma unroll
    for (int j = 0; j < 2; ++j) acc[i][j] = (float4v)(0.f);

  if (bid < 96) {
    const int zz = bid / 12, rem = bid % 12;
    const int b = zz >> 2, c = zz & 3;
    const int y = rem >> 1, x = rem & 1;
    const float* A = base + (size_t)b * 589824 + c * 384 + (size_t)(y * 64) * 1536;
    const unsigned short* Bm =
        haT + (size_t)((b * 4 + c) * 128 + x * 64) * 384;
    gemm_core<0, 1>(A, 1536, Bm, 384, 384, Alds, Blds, t, g,
                    wm0, wn0, col16, quad, acc);
    reduce_groups(acc, (float*)AB, tid);

    if (tid < 256) {
#pragma unroll
      for (int j = 0; j < 2; ++j)
#pragma unroll
        for (int i = 0; i < 2; ++i)
#pragma unroll
          for (int r = 0; r < 4; ++r)
            TA[(wm0 + i * 16 + quad * 4 + r) * 72 + wn0 + j * 16 + col16] =
                f2bf(fast_tanh(acc[i][j][r]));
    }
    {  // W3 slice (64k x 128n) -> TB[n][k], all 512 threads
      const float* W3p = Wmid + 32768 + (size_t)(c * 128 + x * 64) * 128;
      const int kr = tid >> 3, nb = (tid & 7) * 16;
#pragma unroll
      for (int q = 0; q < 4; ++q) {
        float4 v = *(const float4*)(W3p + (size_t)kr * 128 + nb + q * 4);
        TB[(nb + q * 4 + 0) * 72 + kr] = f2bf(v.x);
        TB[(nb + q * 4 + 1) * 72 + kr] = f2bf(v.y);
        TB[(nb + q * 4 + 2) * 72 + kr] = f2bf(v.z);
        TB[(nb + q * 4 + 3) * 72 + kr] = f2bf(v.w);
      }
    }
    __syncthreads();

    if (tid < 256) {
      const int mh = wid2 & 1, nh = wid2 >> 1;
      float4v acc2[2][4];
#pragma unroll
      for (int i = 0; i < 2; ++i)
#pragma unroll
        for (int j = 0; j < 4; ++j) acc2[i][j] = (float4v)(0.f);
#pragma unroll
      for (int ks = 0; ks < 2; ++ks) {
        bf16x8 af[2], bf[4];
#pragma unroll
        for (int i = 0; i < 2; ++i)
          af[i] = __builtin_bit_cast(bf16x8,
              *(const ushort8*)&TA[(mh * 32 + i * 16 + col16) * 72 + ks * 32 + quad * 8]);
#pragma unroll
        for (int j = 0; j < 4; ++j)
          bf[j] = __builtin_bit_cast(bf16x8,
              *(const ushort8*)&TB[(nh * 64 + j * 16 + col16) * 72 + ks * 32 + quad * 8]);
#pragma unroll
        for (int i = 0; i < 2; ++i)
#pragma unroll
          for (int j = 0; j < 4; ++j)
            acc2[i][j] = __builtin_amdgcn_mfma_f32_16x16x32_bf16(
                af[i], bf[j], acc2[i][j], 0, 0, 0);
      }
      float* outp = tref_part + (size_t)(c * 2 + x) * 98304;
#pragma unroll
      for (int j = 0; j < 4; ++j) {
        const int gcol = nh * 64 + j * 16 + col16;
#pragma unroll
        for (int i = 0; i < 2; ++i)
#pragma unroll
          for (int r = 0; r < 4; ++r) {
            const int grow = b * 384 + y * 64 + mh * 32 + i * 16 + quad * 4 + r;
            outp[(size_t)grow * 128 + gcol] = C2 * acc2[i][j][r];
          }
      }
    }
  } else {
    const int idx = bid - 96;
    const int x = idx & 1, y = (idx >> 1) % 48, z = idx / 96;
    const unsigned short* A = tanh16 + (size_t)z * 393216 + (size_t)(y * 64) * 128;
    const float* Bm = Wmid + z * 16384 + x * 64;
    gemm_core<1, 0>(A, 128, Bm, 128, 128, Alds, Blds, t, g,
                    wm0, wn0, col16, quad, acc);
    reduce_groups(acc, (float*)AB, tid);
    if (tid < 256) {
#pragma unroll
      for (int j = 0; j < 2; ++j) {
        const int gcol = x * 64 + wn0 + j * 16 + col16;
#pragma unroll
        for (int i = 0; i < 2; ++i)
#pragma unroll
          for (int r = 0; r < 4; ++r) {
            const int grow = y * 64 + wm0 + i * 16 + quad * 4 + r;
            const float v = C2 * acc[i][j][r];
            const size_t cidx = (size_t)grow * 128 + gcol;
            if (z == 0) tprd_s[cidx] = v;
            else        targ_s[cidx] = f2bf(v);
          }
      }
    }
  }
}

// D3: out[b,p,c,a] = sum_k w_k * tanh(tprd+targ+tref+bmid).
// t_arg row half in registers (8 x uint4); Es (exp2 of per-(p,k) terms,
// now incl. the 8-way tref_part sum) in LDS; cross-kh reduce via Red.
__global__ __launch_bounds__(256) void phase2(
    const float* __restrict__ tprd, const unsigned short* __restrict__ targ,
    const float* __restrict__ tref, const float* __restrict__ bmid,
    const float* __restrict__ wout, float* __restrict__ out)
{
  __shared__ float Es[8 * 128];   // exp2(f[p][k])
  __shared__ float Ws[128];       // -2*w[k]
  __shared__ float Red[128 * 9];  // kh=1 partial sums

  const int tid = threadIdx.x;
  const int a = tid & 127, kh = tid >> 7;
  const int p0 = blockIdx.x * 8, a0 = blockIdx.y * 128;
  const int b = blockIdx.z >> 2, c = blockIdx.z & 3;

  const uint4* grow = (const uint4*)((const unsigned int*)targ +
      (size_t)((b * 384 + a0 + a) * 4 + c) * 64 + kh * 32);
  uint4 G[8];
#pragma unroll
  for (int i = 0; i < 8; ++i) G[i] = grow[i];

  if (tid < 128) Ws[tid] = -2.f * wout[tid];
#pragma unroll
  for (int it = 0; it < 4; ++it) {  // Es[8][128]
    int idx = it * 256 + tid;
    int p = idx >> 7, k = idx & 127;
    int row = b * 384 + p0 + p;
    const float* tr = tref + (size_t)row * 128 + k;
    float s8 = tr[0] + tr[98304] + tr[2 * 98304] + tr[3 * 98304] +
               tr[4 * 98304] + tr[5 * 98304] + tr[6 * 98304] + tr[7 * 98304];
    Es[idx] = __builtin_amdgcn_exp2f(
        tprd[(size_t)(row * 4 + c) * 128 + k] + s8 + C2 * bmid[k]);
  }
  float sw = 0.f;
  for (int k4 = 0; k4 < 32; ++k4) {
    float4 w = ((const float4*)wout)[k4];
    sw += w.x + w.y + w.z + w.w;
  }
  __syncthreads();

  float acc[8];
#pragma unroll
  for (int p = 0; p < 8; ++p) acc[p] = 0.f;

  const int kb0 = kh * 64;
#pragma unroll
  for (int j = 0; j < 8; ++j) {
    const uint4 gq = G[j];
    const float eg0 = __builtin_amdgcn_exp2f(__uint_as_float(gq.x << 16));
    const float eg1 = __builtin_amdgcn_exp2f(__uint_as_float(gq.x & 0xffff0000u));
    const float eg2 = __builtin_amdgcn_exp2f(__uint_as_float(gq.y << 16));
    const float eg3 = __builtin_amdgcn_exp2f(__uint_as_float(gq.y & 0xffff0000u));
    const float eg4 = __builtin_amdgcn_exp2f(__uint_as_float(gq.z << 16));
    const float eg5 = __builtin_amdgcn_exp2f(__uint_as_float(gq.z & 0xffff0000u));
    const float eg6 = __builtin_amdgcn_exp2f(__uint_as_float(gq.w << 16));
    const float eg7 = __builtin_amdgcn_exp2f(__uint_as_float(gq.w & 0xffff0000u));
    const int kb = kb0 + j * 8;
    const float4 wqA = *(const float4*)&Ws[kb];
    const float4 wqB = *(const float4*)&Ws[kb + 4];
#pragma unroll
    for (int p = 0; p < 8; ++p) {
      const float4 efA = *(const float4*)&Es[p * 128 + kb];
      const float4 efB = *(const float4*)&Es[p * 128 + kb + 4];
      float d0 = fmaf(efA.x, eg0, 1.f);
      float d1 = fmaf(efA.y, eg1, 1.f);
      float d2 = fmaf(efA.z, eg2, 1.f);
      float d3 = fmaf(efA.w, eg3, 1.f);
      float d01 = d0 * d1, d23 = d2 * d3;
      float n01 = fmaf(wqA.y, d0, wqA.x * d1);
      float n23 = fmaf(wqA.w, d2, wqA.z * d3);
      float num = fmaf(n01, d23, n23 * d01);
      acc[p] = fmaf(num, __builtin_amdgcn_rcpf(d01 * d23), acc[p]);
      d0 = fmaf(efB.x, eg4, 1.f);
      d1 = fmaf(efB.y, eg5, 1.f);
      d2 = fmaf(efB.z, eg6, 1.f);
      d3 = fmaf(efB.w, eg7, 1.f);
      d01 = d0 * d1; d23 = d2 * d3;
      n01 = fmaf(wqB.y, d0, wqB.x * d1);
      n23 = fmaf(wqB.w, d2, wqB.z * d3);
      num = fmaf(n01, d23, n23 * d01);
      acc[p] = fmaf(num, __builtin_amdgcn_rcpf(d01 * d23), acc[p]);
    }
  }

  if (kh) {
#pragma unroll
    for (int p = 0; p < 8; ++p) Red[a * 9 + p] = acc[p];
  }
  __syncthreads();
  if (!kh) {
    const size_t ob = (size_t)((b * 384 + p0) * 4 + c) * 384 + a0 + a;
#pragma unroll
    for (int p = 0; p < 8; ++p)
      out[ob + (size_t)p * 1536] = sw + acc[p] + Red[a * 9 + p];
  }
}

extern "C" void kernel_launch(void* const* d_in, const int* in_sizes, int n_in,
                              void* d_out, int out_size, void* d_ws, size_t ws_size,
                              hipStream_t stream) {
  (void)in_sizes; (void)n_in; (void)out_size; (void)ws_size;
  const float* seq  = (const float*)d_in[0];
  const float* base = (const float*)d_in[1];
  const float* Wp   = (const float*)d_in[2];
  const float* Wpb  = (const float*)d_in[3];
  const float* Ua   = (const float*)d_in[4];
  const float* Uab  = (const float*)d_in[5];
  const float* Wmid = (const float*)d_in[6];
  const float* bmid = (const float*)d_in[7];
  const float* wout = (const float*)d_in[8];
  float* out = (float*)d_out;

  float* ws = (float*)d_ws;
  unsigned short* tanh16 = (unsigned short*)ws;             // bf16 x2 z
  unsigned short* haT    = (unsigned short*)(ws + 393216);  // bf16, transposed
  float* tprd_s          = ws + 589824;                     // (3072,128) *C2
  unsigned short* targ_s = (unsigned short*)(ws + 983040);  // (3072,128) bf16
  float* tref_part       = ws + 1179648;                    // (8,768,128) *C2

  g1_dual<<<dim3(8, 12, 2), dim3(512), 0, stream>>>(
      seq, Wp, Ua, Wpb, Uab, tanh16, haT);
  fused_mid<<<dim3(288), dim3(512), 0, stream>>>(
      base, haT, tanh16, Wmid, tprd_s, targ_s, tref_part);
  phase2<<<dim3(48, 3, 8), dim3(256), 0, stream>>>(
      tprd_s, targ_s, tref_part, bmid, wout, out);
}